// Round 9
// baseline (395.828 us; speedup 1.0000x reference)
//
#include <hip/hip_runtime.h>

// LinOSS: damped-oscillator linear SSM scan. B=8, T=2048, H=16, D=64.
//   sigma = sigmoid(osc_damp); a = DT*exp(osc_w)   (per h,d,e element)
//   z' = (1-sigma)*z - a*y + DT*beta*k[d]*v[e]
//   y' = y + DT*z'
//   out[b,t,h,e] = (1/8) * sum_d q[b,t,h,d] * y[d,e]
//
// Chunk-parallel over T (constant-coefficient recurrence), two passes:
//   tail: chunks 0..NC-2 from zero state -> final (y,z) to ws.
//   main: chunk c start = sum_i (A^L)^(c-1-i) c_i via 2x2 squarings.
//
// R8 lesson: occupancy axis dead (metadata min caps residency; raising it
// spills). R9 lever: VALU issue is now the floor (~63% busy, half of it
// real work). v_pk_fma_f32/v_pk_mul_f32 (VOP3P dual-f32, CDNA) halves the
// instruction count for state update + q-dot. Compiler never emits these;
// inline asm on float2 register pairs.

constexpr float DTc = 0.01f;
constexpr int Tn = 2048, Hn = 16, Dn = 64;
constexpr int TS = Hn * Dn; // 1024 floats per t-step in q/k/v/out
constexpr int TILE = 16;

typedef const __attribute__((address_space(1))) void* as1_cvp;
typedef __attribute__((address_space(3))) void* as3_vp;

__device__ __forceinline__ void gload_lds4(const float* g, float* lds) {
    // 4B per lane; LDS dst = wave-uniform base + lane*4 (contiguous 256B/wave)
    __builtin_amdgcn_global_load_lds((as1_cvp)g, (as3_vp)lds, 4, 0, 0);
}

__device__ __forceinline__ float2 pk_fma(float2 a, float2 b, float2 c) {
    float2 d;
    asm("v_pk_fma_f32 %0, %1, %2, %3" : "=v"(d) : "v"(a), "v"(b), "v"(c));
    return d;
}
__device__ __forceinline__ float2 pk_mul(float2 a, float2 b) {
    float2 d;
    asm("v_pk_mul_f32 %0, %1, %2" : "=v"(d) : "v"(a), "v"(b));
    return d;
}

// TAIL: chunks 0..NC-2, no q/out, store final state to ws.
// !TAIL: chunks 0..NC-1, reconstruct start state from ws, write out.
template<int NC, bool TAIL>
__global__ __launch_bounds__(256, 4)
void linoss_k(const float* __restrict__ Q, const float* __restrict__ K,
              const float* __restrict__ V, const float* __restrict__ Bt,
              const float* __restrict__ OW, const float* __restrict__ OD,
              float* __restrict__ Out, float* __restrict__ WS) {
    constexpr int L = Tn / NC;
    constexpr bool WQ = !TAIL;

    __shared__ float sK[2][TILE][64];
    __shared__ float sQ[WQ ? 2 : 1][WQ ? TILE : 1][WQ ? 64 : 1];
    __shared__ float sV[2][TILE][32];
    __shared__ float sB[2][TILE];

    int blk = blockIdx.x;
    int c = blk >> 8;       // chunk index
    int sl = blk & 255;
    // XCD-aware decode: both e-halves of the same (b,h) on one XCD.
    int xcd = sl & 7, slot = sl >> 3;
    int ec = slot & 1;
    int bh = ((slot >> 1) << 3) | xcd;
    int b = bh >> 4, h = bh & 15;

    int tid = threadIdx.x;
    int dgrp = tid & 7;
    int el = tid >> 3;
    int e = ec * 32 + el;
    int d0 = dgrp * 8;
    int wv = tid >> 6;      // wave id 0..3
    int ln = tid & 63;      // lane

    // packed per-element constants: 4 x float2 (8 d's)
    float2 nA[4], omc[4];   // nA = -DT*exp(ow); omc = 1-sigmoid(od)
#pragma unroll
    for (int j = 0; j < 4; ++j) {
        int i0 = (h * Dn + d0 + 2 * j) * Dn + e;
        int i1 = (h * Dn + d0 + 2 * j + 1) * Dn + e;
        nA[j].x = -DTc * expf(OW[i0]);
        nA[j].y = -DTc * expf(OW[i1]);
        omc[j].x = 1.0f - 1.0f / (1.0f + expf(-OD[i0]));
        omc[j].y = 1.0f - 1.0f / (1.0f + expf(-OD[i1]));
    }
    const float2 dt2 = {DTc, DTc};

    float2 y[4], z[4];
#pragma unroll
    for (int j = 0; j < 4; ++j) { y[j] = {0.f, 0.f}; z[j] = {0.f, 0.f}; }

    // per-(c,bh,ec) ws tile: 256 threads x 8 elems x {y,z}
    auto wsBase = [&](int ci) {
        return WS + (((size_t)ci * 128 + bh) * 2 + ec) * 4096 + (size_t)tid * 16;
    };

    if (!TAIL && c > 0) {
        // A = [[1+DT*nA, DT*omc],[nA, omc]] on (y,z); A^L by squaring.
        float2 m00[4], m01[4], m10[4], m11[4];
#pragma unroll
        for (int j = 0; j < 4; ++j) {
            m00[j] = pk_fma(dt2, nA[j], {1.f, 1.f});
            m01[j] = pk_mul(dt2, omc[j]);
            m10[j] = nA[j];
            m11[j] = omc[j];
        }
        for (int pw = 1; pw < L; pw <<= 1) {
#pragma unroll
            for (int j = 0; j < 4; ++j) {
                float2 n00 = pk_fma(m00[j], m00[j], pk_mul(m01[j], m10[j]));
                float2 n01 = pk_fma(m00[j], m01[j], pk_mul(m01[j], m11[j]));
                float2 n10 = pk_fma(m10[j], m00[j], pk_mul(m11[j], m10[j]));
                float2 n11 = pk_fma(m10[j], m01[j], pk_mul(m11[j], m11[j]));
                m00[j] = n00; m01[j] = n01; m10[j] = n10; m11[j] = n11;
            }
        }
        for (int i = 0; i < c; ++i) {
            const float4* cw = (const float4*)wsBase(i);
            float4 w0 = cw[0], w1 = cw[1], w2 = cw[2], w3 = cw[3];
            float2 cy[4] = {{w0.x, w0.z}, {w1.x, w1.z}, {w2.x, w2.z}, {w3.x, w3.z}};
            float2 cz[4] = {{w0.y, w0.w}, {w1.y, w1.w}, {w2.y, w2.w}, {w3.y, w3.w}};
#pragma unroll
            for (int j = 0; j < 4; ++j) {
                float2 ny = pk_fma(m00[j], y[j], pk_fma(m01[j], z[j], cy[j]));
                float2 nz = pk_fma(m10[j], y[j], pk_fma(m11[j], z[j], cz[j]));
                y[j] = ny; z[j] = nz;
            }
        }
    }

    // full-row bases (lane covers d / e_local in staging)
    size_t bhOff = (size_t)b * Tn * TS + (size_t)h * Dn;
    const float* kb0 = K + bhOff;
    const float* qb0 = Q + bhOff;
    const float* vb0 = V + bhOff + ec * 32;
    const float* bb0 = Bt + (size_t)b * Tn * Hn + h;
    float* op = Out + bhOff + e;
    bool wlane = (dgrp == 0);

    int t0 = c * L;

    // stage one TILE of k/q/v/beta into LDS buffer `buf` via async DMA
    auto stage = [&](int buf, int tt0) {
#pragma unroll
        for (int j = 0; j < 4; ++j) {
            int s = wv * 4 + j;
            gload_lds4(kb0 + (size_t)(tt0 + s) * TS + ln, &sK[buf][s][0]);
        }
        if (WQ) {
#pragma unroll
            for (int j = 0; j < 4; ++j) {
                int s = wv * 4 + j;
                gload_lds4(qb0 + (size_t)(tt0 + s) * TS + ln, &sQ[buf][s][0]);
            }
        }
#pragma unroll
        for (int jj = 0; jj < 2; ++jj) {
            int m = wv * 2 + jj;
            int step = m * 2 + (ln >> 5);
            gload_lds4(vb0 + (size_t)(tt0 + step) * TS + (ln & 31), &sV[buf][m * 2][0]);
        }
        if (wv == 3 && ln < 16)
            gload_lds4(bb0 + (size_t)(tt0 + ln) * Hn, &sB[buf][0]);
    };

    constexpr int nT = L / TILE;
    stage(0, t0);
    __syncthreads();

    for (int ti = 0; ti < nT; ++ti) {
        int cur = ti & 1;
        if (ti + 1 < nT) stage(cur ^ 1, t0 + (ti + 1) * TILE);
        int tg = t0 + ti * TILE;
#pragma unroll 8
        for (int s = 0; s < TILE; ++s) {
            const float4* kr = (const float4*)&sK[cur][s][d0];
            float4 kA = kr[0], kB = kr[1];
            float vv = sV[cur][s][el];
            float bb = sB[cur][s];
            float bv = (DTc * bb) * vv;
            float2 bv2 = {bv, bv};
            float2 kk[4] = {{kA.x, kA.y}, {kA.z, kA.w}, {kB.x, kB.y}, {kB.z, kB.w}};
#pragma unroll
            for (int j = 0; j < 4; ++j) {
                // z = omc*z + (nA*y + bv*k);  y = y + DT*z
                float2 t2 = pk_fma(nA[j], y[j], pk_mul(bv2, kk[j]));
                z[j] = pk_fma(omc[j], z[j], t2);
                y[j] = pk_fma(dt2, z[j], y[j]);
            }
            if (WQ) {
                const float4* qr = (const float4*)&sQ[cur][s][d0];
                float4 qA = qr[0], qB = qr[1];
                float2 qq[4] = {{qA.x, qA.y}, {qA.z, qA.w}, {qB.x, qB.y}, {qB.z, qB.w}};
                float2 pp = {0.f, 0.f};
#pragma unroll
                for (int j = 0; j < 4; ++j) pp = pk_fma(qq[j], y[j], pp);
                float p = pp.x + pp.y;
                p += __shfl_xor(p, 1);
                p += __shfl_xor(p, 2);
                p += __shfl_xor(p, 4);
                if (wlane) op[(size_t)(tg + s) * TS] = p * 0.125f; // D^-0.5
            }
        }
        __syncthreads();
    }

    if (TAIL) {
        float4* cw = (float4*)wsBase(c);
#pragma unroll
        for (int j = 0; j < 4; ++j) {
            float4 w;
            w.x = y[j].x; w.y = z[j].x;
            w.z = y[j].y; w.w = z[j].y;
            cw[j] = w;
        }
    }
}

extern "C" void kernel_launch(void* const* d_in, const int* in_sizes, int n_in,
                              void* d_out, int out_size, void* d_ws, size_t ws_size,
                              hipStream_t stream) {
    const float* q  = (const float*)d_in[0];
    const float* k  = (const float*)d_in[1];
    const float* v  = (const float*)d_in[2];
    const float* bt = (const float*)d_in[3];
    const float* ow = (const float*)d_in[4];
    const float* od = (const float*)d_in[5];
    float* out = (float*)d_out;
    float* ws = (float*)d_ws;

    const size_t chunkBytes = (size_t)128 * 2 * 4096 * sizeof(float); // 4 MiB

    if (ws_size >= 7 * chunkBytes) {
        // NC=8: main 2048 blocks; tail 1792.
        hipLaunchKernelGGL((linoss_k<8, true>),  dim3(1792), dim3(256), 0, stream,
                           q, k, v, bt, ow, od, out, ws);
        hipLaunchKernelGGL((linoss_k<8, false>), dim3(2048), dim3(256), 0, stream,
                           q, k, v, bt, ow, od, out, ws);
    } else if (ws_size >= 3 * chunkBytes) {
        hipLaunchKernelGGL((linoss_k<4, true>),  dim3(768),  dim3(256), 0, stream,
                           q, k, v, bt, ow, od, out, ws);
        hipLaunchKernelGGL((linoss_k<4, false>), dim3(1024), dim3(256), 0, stream,
                           q, k, v, bt, ow, od, out, ws);
    } else if (ws_size >= chunkBytes) {
        hipLaunchKernelGGL((linoss_k<2, true>),  dim3(256),  dim3(256), 0, stream,
                           q, k, v, bt, ow, od, out, ws);
        hipLaunchKernelGGL((linoss_k<2, false>), dim3(512),  dim3(256), 0, stream,
                           q, k, v, bt, ow, od, out, ws);
    } else {
        hipLaunchKernelGGL((linoss_k<1, false>), dim3(256),  dim3(256), 0, stream,
                           q, k, v, bt, ow, od, out, ws);
    }
}

// Round 11
// 278.941 us; speedup vs baseline: 1.4190x; 1.4190x over previous
//
#include <hip/hip_runtime.h>

// LinOSS: damped-oscillator linear SSM scan. B=8, T=2048, H=16, D=64.
//   sigma = sigmoid(osc_damp); a = DT*exp(osc_w)   (per h,d,e element)
//   z' = (1-sigma)*z - a*y + DT*beta*k[d]*v[e]
//   y' = y + DT*z'
//   out[b,t,h,e] = (1/8) * sum_d q[b,t,h,d] * y[d,e]
//
// Chunk-parallel over T (constant-coefficient recurrence), two passes:
//   tail: chunks 0..NC-2 from zero state -> final (y,z) to ws.
//   main: chunk c start = sum_i (A^L)^(c-1-i) c_i via 2x2 squarings.
//
// R10 lesson: row_ror:4 DPP direction was wrong (mixed e-groups, absmax
// 3e-2). R11: keep width-16 staging + quad_perm DPP (xor1/xor2, exact
// semantics), use proven __shfl_xor for the cross-quad step only.

constexpr float DTc = 0.01f;
constexpr int Tn = 2048, Hn = 16, Dn = 64;
constexpr int TS = Hn * Dn; // 1024 floats per t-step in q/k/v/out
constexpr int TILE = 16;

typedef const __attribute__((address_space(1))) void* as1_cvp;
typedef __attribute__((address_space(3))) void* as3_vp;

__device__ __forceinline__ void gload_lds4(const float* g, float* lds) {
    __builtin_amdgcn_global_load_lds((as1_cvp)g, (as3_vp)lds, 4, 0, 0);
}
__device__ __forceinline__ void gload_lds16(const float* g, float* lds) {
    // 16B per lane; LDS dst = wave-uniform base + lane*16
    __builtin_amdgcn_global_load_lds((as1_cvp)g, (as3_vp)lds, 16, 0, 0);
}

// In-quad butterfly add on the VALU pipe (quad_perm DPP, exact semantics).
template<int CTRL>
__device__ __forceinline__ float dpp_add(float x) {
    int yi = __builtin_amdgcn_update_dpp(0, __float_as_int(x), CTRL, 0xF, 0xF, true);
    return x + __int_as_float(yi);
}

// TAIL: chunks 0..NC-2, no q/out, store final state to ws.
// !TAIL: chunks 0..NC-1, reconstruct start state from ws, write out.
template<int NC, bool TAIL>
__global__ __launch_bounds__(256, 4)
void linoss_k(const float* __restrict__ Q, const float* __restrict__ K,
              const float* __restrict__ V, const float* __restrict__ Bt,
              const float* __restrict__ OW, const float* __restrict__ OD,
              float* __restrict__ Out, float* __restrict__ WS) {
    constexpr int L = Tn / NC;
    constexpr bool WQ = !TAIL;

    __shared__ float sK[2][TILE][64];
    __shared__ float sQ[WQ ? 2 : 1][WQ ? TILE : 1][WQ ? 64 : 1];
    __shared__ float sV[2][TILE][32];
    __shared__ float sB[2][TILE];

    int blk = blockIdx.x;
    int c = blk >> 8;       // chunk index
    int sl = blk & 255;
    // XCD-aware decode: both e-halves of the same (b,h) on one XCD.
    int xcd = sl & 7, slot = sl >> 3;
    int ec = slot & 1;
    int bh = ((slot >> 1) << 3) | xcd;
    int b = bh >> 4, h = bh & 15;

    int tid = threadIdx.x;
    int dgrp = tid & 7;
    int el = tid >> 3;
    int e = ec * 32 + el;
    int d0 = dgrp * 8;
    int wv = tid >> 6;      // wave id 0..3
    int ln = tid & 63;      // lane

    float aDT[8], omc[8];
#pragma unroll
    for (int j = 0; j < 8; ++j) {
        int idx = (h * Dn + d0 + j) * Dn + e;
        aDT[j] = DTc * expf(OW[idx]);
        float sg = 1.0f / (1.0f + expf(-OD[idx]));
        omc[j] = 1.0f - sg;
    }

    float y[8], z[8];
#pragma unroll
    for (int j = 0; j < 8; ++j) { y[j] = 0.0f; z[j] = 0.0f; }

    // per-(c,bh,ec) ws tile: 256 threads x 8 elems x {y,z}
    auto wsBase = [&](int ci) {
        return WS + (((size_t)ci * 128 + bh) * 2 + ec) * 4096 + (size_t)tid * 16;
    };

    if (!TAIL && c > 0) {
        // A = [[1-DT*a, DT*w],[-a, w]] on (y,z); compute A^L by squaring.
        float m00[8], m01[8], m10[8], m11[8];
#pragma unroll
        for (int j = 0; j < 8; ++j) {
            m00[j] = 1.0f - DTc * aDT[j];
            m01[j] = DTc * omc[j];
            m10[j] = -aDT[j];
            m11[j] = omc[j];
        }
        for (int pw = 1; pw < L; pw <<= 1) {
#pragma unroll
            for (int j = 0; j < 8; ++j) {
                float n00 = fmaf(m00[j], m00[j], m01[j] * m10[j]);
                float n01 = fmaf(m00[j], m01[j], m01[j] * m11[j]);
                float n10 = fmaf(m10[j], m00[j], m11[j] * m10[j]);
                float n11 = fmaf(m10[j], m01[j], m11[j] * m11[j]);
                m00[j] = n00; m01[j] = n01; m10[j] = n10; m11[j] = n11;
            }
        }
        for (int i = 0; i < c; ++i) {
            const float4* cw = (const float4*)wsBase(i);
            float4 w0 = cw[0], w1 = cw[1], w2 = cw[2], w3 = cw[3];
            float cy[8] = {w0.x, w0.z, w1.x, w1.z, w2.x, w2.z, w3.x, w3.z};
            float cz[8] = {w0.y, w0.w, w1.y, w1.w, w2.y, w2.w, w3.y, w3.w};
#pragma unroll
            for (int j = 0; j < 8; ++j) {
                float ny = fmaf(m00[j], y[j], fmaf(m01[j], z[j], cy[j]));
                float nz = fmaf(m10[j], y[j], fmaf(m11[j], z[j], cz[j]));
                y[j] = ny; z[j] = nz;
            }
        }
    }

    // full-row bases
    size_t bhOff = (size_t)b * Tn * TS + (size_t)h * Dn;
    const float* kb0 = K + bhOff;
    const float* qb0 = Q + bhOff;
    const float* vb0 = V + bhOff + ec * 32;
    const float* bb0 = Bt + (size_t)b * Tn * Hn + h;
    float* op = Out + bhOff + e;
    bool wlane = (dgrp == 0);

    int t0 = c * L;

    // stage one TILE (16 steps) into LDS buffer `buf` via width-16 DMA.
    // K/Q rows: 64 floats = 256B -> 16 lanes/row, 4 rows/inst, 1 inst/wave.
    // V rows: 32 floats = 128B -> 8 lanes/row, 8 rows/inst, insts on wv 0,1.
    // B: width-4, 16 lanes, on wv 2.
    auto stage = [&](int buf, int tt0) {
        {
            int row = 4 * wv + (ln >> 4);
            const float* src = kb0 + (size_t)(tt0 + row) * TS + (ln & 15) * 4;
            gload_lds16(src, &sK[buf][4 * wv][0]);
        }
        if (WQ) {
            int row = 4 * wv + (ln >> 4);
            const float* src = qb0 + (size_t)(tt0 + row) * TS + (ln & 15) * 4;
            gload_lds16(src, &sQ[buf][4 * wv][0]);
        }
        if (wv < 2) {
            int row = 8 * wv + (ln >> 3);
            const float* src = vb0 + (size_t)(tt0 + row) * TS + (ln & 7) * 4;
            gload_lds16(src, &sV[buf][8 * wv][0]);
        }
        if (wv == 2 && ln < 16)
            gload_lds4(bb0 + (size_t)(tt0 + ln) * Hn, &sB[buf][0]);
    };

    constexpr int nT = L / TILE;
    stage(0, t0);
    __syncthreads();

    for (int ti = 0; ti < nT; ++ti) {
        int cur = ti & 1;
        if (ti + 1 < nT) stage(cur ^ 1, t0 + (ti + 1) * TILE);
        float* ops = op + (size_t)(t0 + ti * TILE) * TS;
#pragma unroll 8
        for (int s = 0; s < TILE; ++s) {
            const float4* kr = (const float4*)&sK[cur][s][d0];
            float4 ka = kr[0], kb = kr[1];
            float vv = sV[cur][s][el];
            float bb = sB[cur][s];
            float bv = (DTc * bb) * vv;
            float kk[8] = {ka.x, ka.y, ka.z, ka.w, kb.x, kb.y, kb.z, kb.w};
#pragma unroll
            for (int j = 0; j < 8; ++j) {
                z[j] = fmaf(omc[j], z[j], fmaf(-aDT[j], y[j], bv * kk[j]));
                y[j] = fmaf(DTc, z[j], y[j]);
            }
            if (WQ) {
                const float4* qr = (const float4*)&sQ[cur][s][d0];
                float4 qa = qr[0], qb = qr[1];
                float qq[8] = {qa.x, qa.y, qa.z, qa.w, qb.x, qb.y, qb.z, qb.w};
                float p = 0.0f;
#pragma unroll
                for (int j = 0; j < 8; ++j) p = fmaf(qq[j], y[j], p);
                p = dpp_add<0xB1>(p);   // quad_perm xor1 (exact)
                p = dpp_add<0x4E>(p);   // quad_perm xor2 (exact)
                p += __shfl_xor(p, 4);  // cross-quad (proven)
                if (wlane) *ops = p * 0.125f; // scale = D^-0.5
                ops += TS;
            }
        }
        __syncthreads();
    }

    if (TAIL) {
        float4* cw = (float4*)wsBase(c);
#pragma unroll
        for (int j = 0; j < 4; ++j) {
            float4 w;
            w.x = y[2 * j];     w.y = z[2 * j];
            w.z = y[2 * j + 1]; w.w = z[2 * j + 1];
            cw[j] = w;
        }
    }
}

extern "C" void kernel_launch(void* const* d_in, const int* in_sizes, int n_in,
                              void* d_out, int out_size, void* d_ws, size_t ws_size,
                              hipStream_t stream) {
    const float* q  = (const float*)d_in[0];
    const float* k  = (const float*)d_in[1];
    const float* v  = (const float*)d_in[2];
    const float* bt = (const float*)d_in[3];
    const float* ow = (const float*)d_in[4];
    const float* od = (const float*)d_in[5];
    float* out = (float*)d_out;
    float* ws = (float*)d_ws;

    const size_t chunkBytes = (size_t)128 * 2 * 4096 * sizeof(float); // 4 MiB

    if (ws_size >= 7 * chunkBytes) {
        // NC=8: main 2048 blocks; tail 1792.
        hipLaunchKernelGGL((linoss_k<8, true>),  dim3(1792), dim3(256), 0, stream,
                           q, k, v, bt, ow, od, out, ws);
        hipLaunchKernelGGL((linoss_k<8, false>), dim3(2048), dim3(256), 0, stream,
                           q, k, v, bt, ow, od, out, ws);
    } else if (ws_size >= 3 * chunkBytes) {
        hipLaunchKernelGGL((linoss_k<4, true>),  dim3(768),  dim3(256), 0, stream,
                           q, k, v, bt, ow, od, out, ws);
        hipLaunchKernelGGL((linoss_k<4, false>), dim3(1024), dim3(256), 0, stream,
                           q, k, v, bt, ow, od, out, ws);
    } else if (ws_size >= chunkBytes) {
        hipLaunchKernelGGL((linoss_k<2, true>),  dim3(256),  dim3(256), 0, stream,
                           q, k, v, bt, ow, od, out, ws);
        hipLaunchKernelGGL((linoss_k<2, false>), dim3(512),  dim3(256), 0, stream,
                           q, k, v, bt, ow, od, out, ws);
    } else {
        hipLaunchKernelGGL((linoss_k<1, false>), dim3(256),  dim3(256), 0, stream,
                           q, k, v, bt, ow, od, out, ws);
    }
}